// Round 2
// baseline (112.468 us; speedup 1.0000x reference)
//
#include <hip/hip_runtime.h>
#include <hip/hip_bf16.h>
#include <math.h>

#define Bn 4
#define Cn 64
#define Pn 4096   // 64*64
#define QT 32     // q-tile per block (R15: 512 blocks -> 2 blocks/CU, 4 waves/SIMD)
#define PBK 128   // p-block per flash iteration
#define NITER (Pn / PBK)
#define LOG2E 1.4426950408889634f

typedef __attribute__((ext_vector_type(8))) short short8;   // 8 bf16 (MFMA K=32 A/B frag)
typedef __attribute__((ext_vector_type(4))) short short4v;  // 4 bf16 (MFMA K=16 A/B frag)
typedef __attribute__((ext_vector_type(4))) float float4v;  // MFMA C/D frag
typedef unsigned short bfu;

__device__ __forceinline__ bfu f2bf(float x) {
    unsigned u = __float_as_uint(x);
    u = (u + 0x7fffu + ((u >> 16) & 1u)) >> 16;   // RNE; inputs finite
    return (bfu)u;
}

// ---------------------------------------------------------------------------
// Prep (unchanged): 768 blocks, 16KB LDS.
//   blocks [0,512):   knorm -> bf16 Kpc [B][P][C]  and tiled Kcp2 [B][P/16][C][16p]
//   blocks [512,768): 3x3 zero-padded box-sum * log2(e) -> S [B][C][P]
// ---------------------------------------------------------------------------
__global__ __launch_bounds__(256) void prep_kernel(const float* __restrict__ fg,
                                                   bfu* __restrict__ Kpc,
                                                   bfu* __restrict__ Kcp2,
                                                   float* __restrict__ S) {
    __shared__ float shbuf[64 * 64];
    int t = threadIdx.x;
    if (blockIdx.x < 512) {
        float* tile  = shbuf;            // [64c][32p] stride 33
        float* rnorm = shbuf + 64 * 33;
        int b  = blockIdx.x >> 7;
        int p0 = (blockIdx.x & 127) << 5;
        const float* src = fg + (size_t)b * Cn * Pn + p0;
        #pragma unroll
        for (int i = 0; i < 8; ++i) {
            int idx = i * 256 + t;
            int c = idx >> 5, p = idx & 31;
            tile[c * 33 + p] = src[(size_t)c * Pn + p];
        }
        __syncthreads();
        if (t < 32) {
            float ss = 0.f;
            #pragma unroll
            for (int c = 0; c < 64; ++c) { float v = tile[c * 33 + t]; ss += v * v; }
            rnorm[t] = 1.0f / (sqrtf(ss) + 1e-8f);
        }
        __syncthreads();
        bfu* dpc = Kpc + ((size_t)b * Pn + p0) * Cn;
        #pragma unroll
        for (int i = 0; i < 8; ++i) {
            int idx = i * 256 + t;
            int p = idx >> 6, c = idx & 63;
            dpc[(size_t)p * Cn + c] = f2bf(tile[c * 33 + p] * rnorm[p]);
        }
        // tiled transpose layout: Kcp2[b][pt][c][pl], pt = p>>4, pl = p&15
        bfu* d2 = Kcp2 + ((size_t)b * 256 + (p0 >> 4)) * 1024;
        #pragma unroll
        for (int i = 0; i < 8; ++i) {
            int idx = i * 256 + t;
            int c = idx >> 5, p = idx & 31;
            d2[(size_t)(p >> 4) * 1024 + c * 16 + (p & 15)] =
                f2bf(tile[c * 33 + p] * rnorm[p]);
        }
    } else {
        float (*pl)[64] = (float(*)[64])shbuf;
        int bc = blockIdx.x - 512;
        const float* src = fg + (size_t)bc * Pn;
        float*       dst = S  + (size_t)bc * Pn;
        #pragma unroll
        for (int i = 0; i < 16; ++i) {
            int idx = i * 256 + t;
            pl[idx >> 6][idx & 63] = src[idx];
        }
        __syncthreads();
        #pragma unroll
        for (int i = 0; i < 16; ++i) {
            int idx = i * 256 + t;
            int h = idx >> 6, w = idx & 63;
            float s = 0.f;
            #pragma unroll
            for (int dh = -1; dh <= 1; ++dh) {
                int hh = h + dh;
                if (hh < 0 || hh >= 64) continue;
                #pragma unroll
                for (int dw = -1; dw <= 1; ++dw) {
                    int ww = w + dw;
                    if (ww < 0 || ww >= 64) continue;
                    s += pl[hh][ww];
                }
            }
            dst[idx] = s * LOG2E;
        }
    }
}

// ---------------------------------------------------------------------------
// Flash, ZERO-LDS K-loop. R15: QT=32, 512 blocks x 512 thr -> 2 blocks/CU,
// 4 waves/SIMD (was 2 in R13). Per-wave state halved to fit 128 VGPR.
// bf16 pack: known-good scalar f2bf (R14's cvt_pk asm produced NaN - reverted).
// Wave w owns p-rows [16w,16w+16) of each 128-p block end-to-end:
//   score: A = global Kpc rows (dwordx4), B = hoisted S frags (K=32 MFMA x4)
//   exp'd scores -> register K=16 A-frags (C-layout == A-layout)
//   accum: B = global Kcp2 frags (dwordx2), K=16 MFMA x8; loads prefetched
//   one iteration ahead. No LDS, no barriers inside the loop.
// ---------------------------------------------------------------------------
__global__ __launch_bounds__(512, 4) void flash_kernel(const bfu* __restrict__ Kpc,
                                                       const bfu* __restrict__ Kcp2,
                                                       const float* __restrict__ S,
                                                       float* __restrict__ out) {
    // Sl lives in [0,2048) bfu; epilogue Ol fp32 [4][64][34] overlays (34816 B)
    __shared__ __align__(16) bfu smem[17408];
    __shared__ float wredl[8][QT];
    bfu* Sl = smem;

    int i  = blockIdx.x;
    int b  = (i & 7) >> 1;                       // XCD-pair locality
    int qt = ((i >> 3) << 1) | (i & 1);          // [0,128)
    int q0 = qt * QT;
    int t  = threadIdx.x;
    int w = t >> 6, l = t & 63, lq = l & 15, quad = l >> 4;

    const float* Sg  = S    + (size_t)b * Cn * Pn;
    const bfu*   gpc = Kpc  + (size_t)b * Pn * Cn;
    const bfu*   gt  = Kcp2 + (size_t)b * 256 * 1024;   // [pt][c][pl]

    // Sl[q][c] = bf16(Sg[c][q0+q]) (S pre-scaled by log2e), XOR-swizzled rows
    {
        int c = t >> 3, qq = (t & 7) * 4;
        const float* sp = &Sg[(size_t)c * Pn + q0 + qq];
        float4 v0 = *(const float4*)sp;
        float vv[4] = {v0.x, v0.y, v0.z, v0.w};
        int ch = c >> 3, cl = c & 7;
        #pragma unroll
        for (int k = 0; k < 4; ++k) {
            int row = qq + k;
            Sl[row * 64 + ((ch ^ (row & 7)) << 3) + cl] = f2bf(vv[k]);
        }
    }
    __syncthreads();   // Sl visible

    // hoist S B-frags: B[k=c][n=q], n=lq(+16nt), k=quad*8+j (+32ks)
    short8 bs[2][2];
    #pragma unroll
    for (int nt = 0; nt < 2; ++nt)
        #pragma unroll
        for (int ks = 0; ks < 2; ++ks) {
            int row = nt * 16 + lq;
            bs[nt][ks] = *(const short8*)&Sl[row * 64 + (((ks * 4 + quad) ^ (lq & 7)) << 3)];
        }

    float4v o[2][4];   // [nt][cb]: q = 16nt+4quad+r, c = 16cb+lq (wave-private p-partial)
    #pragma unroll
    for (int nt = 0; nt < 2; ++nt)
        #pragma unroll
        for (int cb = 0; cb < 4; ++cb) o[nt][cb] = (float4v){0.f, 0.f, 0.f, 0.f};
    float lacc[2] = {0.f, 0.f};

    // per-wave global addresses (advance by constants each iteration)
    const bfu* ap = gpc + ((size_t)16 * w + lq) * Cn + quad * 8;           // score A rows
    const bfu* tp = gt + (size_t)w * 1024 + lq * 16 + quad * 4;            // accum B frags

    // prologue: load pb=0 operands
    float4 a0 = *(const float4*)ap;
    float4 a1 = *(const float4*)(ap + 32);
    short4v kb[4];
    #pragma unroll
    for (int cb = 0; cb < 4; ++cb) kb[cb] = *(const short4v*)(tp + cb * 256);

    for (int pb = 0; pb < NITER; ++pb) {
        // ---- prefetch pb+1 operands (independent; compiler issues early) ----
        float4 na0, na1;
        short4v nkb[4];
        if (pb + 1 < NITER) {
            const bfu* apn = ap + (size_t)(pb + 1) * PBK * Cn;
            na0 = *(const float4*)apn;
            na1 = *(const float4*)(apn + 32);
            const bfu* tpn = tp + (size_t)(pb + 1) * 8 * 1024;
            #pragma unroll
            for (int cb = 0; cb < 4; ++cb) nkb[cb] = *(const short4v*)(tpn + cb * 256);
        }

        // ---- score GEMM (K=32): D[m=p][n=q], 2 q-subtiles ----
        short8 af0 = *(short8*)&a0, af1 = *(short8*)&a1;
        float4v sc[2];
        #pragma unroll
        for (int nt = 0; nt < 2; ++nt) {
            float4v acc = (float4v){0.f, 0.f, 0.f, 0.f};
            acc = __builtin_amdgcn_mfma_f32_16x16x32_bf16(af0, bs[nt][0], acc, 0, 0, 0);
            acc = __builtin_amdgcn_mfma_f32_16x16x32_bf16(af1, bs[nt][1], acc, 0, 0, 0);
            sc[nt] = acc;
        }

        // ---- exp2 + denominator; pack E directly as K=16 A-frags ----
        short4v epk[2];
        #pragma unroll
        for (int nt = 0; nt < 2; ++nt) {
            float e0 = __builtin_amdgcn_exp2f(sc[nt][0]);
            float e1 = __builtin_amdgcn_exp2f(sc[nt][1]);
            float e2 = __builtin_amdgcn_exp2f(sc[nt][2]);
            float e3 = __builtin_amdgcn_exp2f(sc[nt][3]);
            lacc[nt] += (e0 + e1) + (e2 + e3);
            short4v ep = {(short)f2bf(e0), (short)f2bf(e1), (short)f2bf(e2), (short)f2bf(e3)};
            epk[nt] = ep;
        }

        // ---- accum GEMM (K=16): o'[q][c] += E · Kcp2 frags ----
        #pragma unroll
        for (int cb = 0; cb < 4; ++cb) {
            #pragma unroll
            for (int nt = 0; nt < 2; ++nt)
                o[nt][cb] = __builtin_amdgcn_mfma_f32_16x16x16bf16_1k(epk[nt], kb[cb], o[nt][cb], 0, 0, 0);
        }

        // rotate prefetched operands
        a0 = na0; a1 = na1;
        #pragma unroll
        for (int cb = 0; cb < 4; ++cb) kb[cb] = nkb[cb];
    }

    // ---- denominator: quad-reduce then stash per wave ----
    #pragma unroll
    for (int nt = 0; nt < 2; ++nt) {
        lacc[nt] += __shfl_xor(lacc[nt], 16);
        lacc[nt] += __shfl_xor(lacc[nt], 32);
    }
    if (quad == 0)
        #pragma unroll
        for (int nt = 0; nt < 2; ++nt) wredl[w][nt * 16 + lq] = lacc[nt];

    // ---- cross-wave combine via LDS overlay (2 rounds) ----
    float* Ol = (float*)smem;   // [4][64 c][34] fp32 = 34816 B
    __syncthreads();            // Sl reads done; wredl visible
    if (w < 4) {
        #pragma unroll
        for (int nt = 0; nt < 2; ++nt)
            #pragma unroll
            for (int cb = 0; cb < 4; ++cb)
                #pragma unroll
                for (int r = 0; r < 4; ++r)
                    Ol[(w * 64 + 16 * cb + lq) * 34 + nt * 16 + quad * 4 + r] = o[nt][cb][r];
    }
    __syncthreads();
    if (w >= 4) {
        #pragma unroll
        for (int nt = 0; nt < 2; ++nt)
            #pragma unroll
            for (int cb = 0; cb < 4; ++cb)
                #pragma unroll
                for (int r = 0; r < 4; ++r)
                    Ol[((w - 4) * 64 + 16 * cb + lq) * 34 + nt * 16 + quad * 4 + r] += o[nt][cb][r];
    }
    __syncthreads();

    // ---- final: out[c][q0+q] = sum of 4 buffers / l_q ----
    float* og = out + (size_t)b * Cn * Pn;
    #pragma unroll
    for (int k = 0; k < 4; ++k) {
        int idx = k * 512 + t;
        int c = idx >> 5, q = idx & 31;
        float lsum = ((wredl[0][q] + wredl[1][q]) + (wredl[2][q] + wredl[3][q])) +
                     ((wredl[4][q] + wredl[5][q]) + (wredl[6][q] + wredl[7][q]));
        float v = ((Ol[c * 34 + q] + Ol[(64 + c) * 34 + q]) +
                   (Ol[(128 + c) * 34 + q] + Ol[(192 + c) * 34 + q])) / lsum;
        og[(size_t)c * Pn + q0 + q] = v;
    }
}

// ---------------------------------------------------------------------------
extern "C" void kernel_launch(void* const* d_in, const int* in_sizes, int n_in,
                              void* d_out, int out_size, void* d_ws, size_t ws_size,
                              hipStream_t stream) {
    const float* fg = (const float*)d_in[0];
    float* out = (float*)d_out;
    bfu*   Kpc  = (bfu*)d_ws;                              // 2 MB  bf16 [B][P][C]
    bfu*   Kcp2 = Kpc + (size_t)Bn * Pn * Cn;              // 2 MB  bf16 [B][P/16][C][16]
    float* S    = (float*)(Kcp2 + (size_t)Bn * Pn * Cn);   // 4 MB  fp32 [B][C][P] (pre-scaled by log2e)

    prep_kernel <<<768, 256, 0, stream>>>(fg, Kpc, Kcp2, S);
    flash_kernel<<<Bn * 128, 512, 0, stream>>>(Kpc, Kcp2, S, out);
}

// Round 3
// 94.896 us; speedup vs baseline: 1.1852x; 1.1852x over previous
//
#include <hip/hip_runtime.h>
#include <hip/hip_bf16.h>
#include <math.h>

#define Bn 4
#define Cn 64
#define Pn 4096   // 64*64
#define QT 64     // q-tile per block (R16: back to 256 blocks, halves L2 traffic)
#define PBK 128   // p-block per flash iteration
#define NITER (Pn / PBK)
#define LOG2E 1.4426950408889634f

// LDS staging: 3 buffers x 32KB (A 16KB + T 16KB per 128-p tile), then Sl 8KB.
#define STG_BUF 32768
#define SL_OFF  98304          // 3*32768
#define SMEM_BYTES 106496      // SL_OFF + 8192

typedef __attribute__((ext_vector_type(8))) short short8;   // 8 bf16 (MFMA K=32 A/B frag)
typedef __attribute__((ext_vector_type(4))) short short4v;  // 4 bf16 (MFMA K=16 A/B frag)
typedef __attribute__((ext_vector_type(4))) float float4v;  // MFMA C/D frag
typedef unsigned short bfu;

__device__ __forceinline__ bfu f2bf(float x) {
    unsigned u = __float_as_uint(x);
    u = (u + 0x7fffu + ((u >> 16) & 1u)) >> 16;   // RNE; inputs finite
    return (bfu)u;
}

// async global->LDS, 16B per lane. LDS dest = wave-uniform base + lane*16.
__device__ __forceinline__ void gl16(const bfu* g, void* l) {
    __builtin_amdgcn_global_load_lds(
        (const __attribute__((address_space(1))) void*)g,
        (__attribute__((address_space(3))) void*)l, 16, 0, 0);
}

// ---------------------------------------------------------------------------
// Prep (unchanged): 768 blocks, 16KB LDS.
//   blocks [0,512):   knorm -> bf16 Kpc [B][P][C]  and tiled Kcp2 [B][P/16][C][16p]
//   blocks [512,768): 3x3 zero-padded box-sum * log2(e) -> S [B][C][P]
// ---------------------------------------------------------------------------
__global__ __launch_bounds__(256) void prep_kernel(const float* __restrict__ fg,
                                                   bfu* __restrict__ Kpc,
                                                   bfu* __restrict__ Kcp2,
                                                   float* __restrict__ S) {
    __shared__ float shbuf[64 * 64];
    int t = threadIdx.x;
    if (blockIdx.x < 512) {
        float* tile  = shbuf;            // [64c][32p] stride 33
        float* rnorm = shbuf + 64 * 33;
        int b  = blockIdx.x >> 7;
        int p0 = (blockIdx.x & 127) << 5;
        const float* src = fg + (size_t)b * Cn * Pn + p0;
        #pragma unroll
        for (int i = 0; i < 8; ++i) {
            int idx = i * 256 + t;
            int c = idx >> 5, p = idx & 31;
            tile[c * 33 + p] = src[(size_t)c * Pn + p];
        }
        __syncthreads();
        if (t < 32) {
            float ss = 0.f;
            #pragma unroll
            for (int c = 0; c < 64; ++c) { float v = tile[c * 33 + t]; ss += v * v; }
            rnorm[t] = 1.0f / (sqrtf(ss) + 1e-8f);
        }
        __syncthreads();
        bfu* dpc = Kpc + ((size_t)b * Pn + p0) * Cn;
        #pragma unroll
        for (int i = 0; i < 8; ++i) {
            int idx = i * 256 + t;
            int p = idx >> 6, c = idx & 63;
            dpc[(size_t)p * Cn + c] = f2bf(tile[c * 33 + p] * rnorm[p]);
        }
        // tiled transpose layout: Kcp2[b][pt][c][pl], pt = p>>4, pl = p&15
        bfu* d2 = Kcp2 + ((size_t)b * 256 + (p0 >> 4)) * 1024;
        #pragma unroll
        for (int i = 0; i < 8; ++i) {
            int idx = i * 256 + t;
            int c = idx >> 5, p = idx & 31;
            d2[(size_t)(p >> 4) * 1024 + c * 16 + (p & 15)] =
                f2bf(tile[c * 33 + p] * rnorm[p]);
        }
    } else {
        float (*pl)[64] = (float(*)[64])shbuf;
        int bc = blockIdx.x - 512;
        const float* src = fg + (size_t)bc * Pn;
        float*       dst = S  + (size_t)bc * Pn;
        #pragma unroll
        for (int i = 0; i < 16; ++i) {
            int idx = i * 256 + t;
            pl[idx >> 6][idx & 63] = src[idx];
        }
        __syncthreads();
        #pragma unroll
        for (int i = 0; i < 16; ++i) {
            int idx = i * 256 + t;
            int h = idx >> 6, w = idx & 63;
            float s = 0.f;
            #pragma unroll
            for (int dh = -1; dh <= 1; ++dh) {
                int hh = h + dh;
                if (hh < 0 || hh >= 64) continue;
                #pragma unroll
                for (int dw = -1; dw <= 1; ++dw) {
                    int ww = w + dw;
                    if (ww < 0 || ww >= 64) continue;
                    s += pl[hh][ww];
                }
            }
            dst[idx] = s * LOG2E;
        }
    }
}

// ---------------------------------------------------------------------------
// Flash with async LDS pipeline (R16). QT=64, 256 blocks x 512 thr.
// Wave w owns p-rows [16w,16w+16) of each 128-p tile end-to-end; staging is
// WAVE-PRIVATE: each wave global_load_lds's its own A rows (source-address
// XOR-swizzled, linear LDS dest, swizzled ds_read -> conflict-free) and its
// own Kcp2 frags (linear). 3 buffers, issue tile pb+2, counted vmcnt(8) --
// never 0 in the main loop. No barriers inside the K-loop.
// ---------------------------------------------------------------------------
__global__ __launch_bounds__(512, 1) void flash_kernel(const bfu* __restrict__ Kpc,
                                                       const bfu* __restrict__ Kcp2,
                                                       const float* __restrict__ S,
                                                       float* __restrict__ out) {
    __shared__ __align__(16) unsigned char smem[SMEM_BYTES];
    __shared__ float wredl[8][QT];
    bfu* Sl = (bfu*)(smem + SL_OFF);       // [64q][64c] bf16, XOR-swizzled rows

    int i  = blockIdx.x;
    int b  = (i & 7) >> 1;                 // XCD-pair locality (batch per XCD pair)
    int qt = ((i >> 3) << 1) | (i & 1);    // [0,64)
    int q0 = qt * QT;
    int t  = threadIdx.x;
    int w = t >> 6, l = t & 63, lq = l & 15, quad = l >> 4;

    const float* Sg  = S    + (size_t)b * Cn * Pn;
    const bfu*   gpc = Kpc  + (size_t)b * Pn * Cn;
    const bfu*   gt  = Kcp2 + (size_t)b * 256 * 1024;   // [pt][c][pl]

    // Sl[q][c] = bf16(Sg[c][q0+q]) (S pre-scaled by log2e), XOR-swizzled rows
    {
        int c = t >> 3, qq = (t & 7) * 8;
        const float* sp = &Sg[(size_t)c * Pn + q0 + qq];
        float4 v0 = *(const float4*)sp;
        float4 v1 = *(const float4*)(sp + 4);
        float vv[8] = {v0.x, v0.y, v0.z, v0.w, v1.x, v1.y, v1.z, v1.w};
        int ch = c >> 3, cl = c & 7;
        #pragma unroll
        for (int k = 0; k < 8; ++k) {
            int row = qq + k;
            Sl[row * 64 + ((ch ^ (row & 7)) << 3) + cl] = f2bf(vv[k]);
        }
    }
    __syncthreads();   // Sl visible

    // hoist S B-frags: B[k=c][n=q], n=lq(+16nt), k=quad*8+j (+32ks)
    short8 bs[4][2];
    #pragma unroll
    for (int nt = 0; nt < 4; ++nt)
        #pragma unroll
        for (int ks = 0; ks < 2; ++ks) {
            int row = nt * 16 + lq;
            bs[nt][ks] = *(const short8*)&Sl[row * 64 + (((ks * 4 + quad) ^ (lq & 7)) << 3)];
        }

    float4v o[4][4];   // [nt][cb]: q = 16nt+4quad+r, c = 16cb+lq (wave-private p-partial)
    #pragma unroll
    for (int nt = 0; nt < 4; ++nt)
        #pragma unroll
        for (int cb = 0; cb < 4; ++cb) o[nt][cb] = (float4v){0.f, 0.f, 0.f, 0.f};
    float lacc[4] = {0.f, 0.f, 0.f, 0.f};

    // ---- per-lane staging offsets --------------------------------------
    // A-chunk [16 rows][128B]; LDS slot (row, s) holds global slot s^(row&7)
    // => source elem = row*64 + 8*((l&7) ^ (l>>3)), row = j*8 + (l>>3)
    int l8 = l >> 3, l7 = l & 7;
    int aoff = l8 * 64 + (((l7 ^ l8)) << 3);     // elements; +j*512 per instr
    int toff = l * 8;                            // elements; +j*512 per instr (linear)
    // per-lane read offsets (bytes within buffer)
    int abyte0 = lq * 128 + (((quad)     ^ (lq & 7)) << 4);
    int abyte1 = lq * 128 + (((4 + quad) ^ (lq & 7)) << 4);
    int tbyte  = 16384 + lq * 32 + quad * 8;     // T chunk at +16KB within buffer

    unsigned wb = (unsigned)w * 2048;            // wave's A sub-chunk byte base
    unsigned ro = 0 * STG_BUF, mo = 1 * STG_BUF, io = 2 * STG_BUF;

    #define ISSUE(tile, boff)                                                      \
    {                                                                              \
        const bfu* gA = gpc + ((size_t)(tile) * PBK + (size_t)w * 16) * 64;        \
        const bfu* gT = gt + ((size_t)(tile) * 8 + w) * 1024;                      \
        gl16(gA + aoff,       smem + (boff) + wb);                                 \
        gl16(gA + 512 + aoff, smem + (boff) + wb + 1024);                          \
        gl16(gT + toff,       smem + (boff) + 16384 + wb);                         \
        gl16(gT + 512 + toff, smem + (boff) + 16384 + wb + 1024);                  \
    }

    // prologue: stage tiles 0 and 1
    ISSUE(0, ro);
    ISSUE(1, mo);

    for (int pb = 0; pb < NITER; ++pb) {
        // ---- issue tile pb+2, then wait so tile pb (oldest 4 loads) is done ----
        if (pb < NITER - 2) {
            ISSUE(pb + 2, io);
            asm volatile("s_waitcnt vmcnt(8)" ::: "memory");
        } else if (pb == NITER - 2) {
            asm volatile("s_waitcnt vmcnt(4)" ::: "memory");
        } else {
            asm volatile("s_waitcnt vmcnt(0)" ::: "memory");
        }

        // ---- LDS -> register fragments for tile pb ----
        short8 af0 = *(const short8*)(smem + ro + wb + abyte0);
        short8 af1 = *(const short8*)(smem + ro + wb + abyte1);
        short4v kb[4];
        #pragma unroll
        for (int cb = 0; cb < 4; ++cb)
            kb[cb] = *(const short4v*)(smem + ro + wb * 0 + (unsigned)w * 2048 + tbyte + cb * 512);

        // ---- score GEMM (K=32): D[m=p][n=q], 4 q-subtiles ----
        float4v sc[4];
        #pragma unroll
        for (int nt = 0; nt < 4; ++nt) {
            float4v acc = (float4v){0.f, 0.f, 0.f, 0.f};
            acc = __builtin_amdgcn_mfma_f32_16x16x32_bf16(af0, bs[nt][0], acc, 0, 0, 0);
            acc = __builtin_amdgcn_mfma_f32_16x16x32_bf16(af1, bs[nt][1], acc, 0, 0, 0);
            sc[nt] = acc;
        }

        // ---- exp2 + denominator; pack E directly as K=16 A-frags ----
        short4v epk[4];
        #pragma unroll
        for (int nt = 0; nt < 4; ++nt) {
            float e0 = __builtin_amdgcn_exp2f(sc[nt][0]);
            float e1 = __builtin_amdgcn_exp2f(sc[nt][1]);
            float e2 = __builtin_amdgcn_exp2f(sc[nt][2]);
            float e3 = __builtin_amdgcn_exp2f(sc[nt][3]);
            lacc[nt] += (e0 + e1) + (e2 + e3);
            short4v ep = {(short)f2bf(e0), (short)f2bf(e1), (short)f2bf(e2), (short)f2bf(e3)};
            epk[nt] = ep;
        }

        // ---- accum GEMM (K=16): o'[q][c] += E · Kcp2 frags ----
        #pragma unroll
        for (int cb = 0; cb < 4; ++cb) {
            #pragma unroll
            for (int nt = 0; nt < 4; ++nt)
                o[nt][cb] = __builtin_amdgcn_mfma_f32_16x16x16bf16_1k(epk[nt], kb[cb], o[nt][cb], 0, 0, 0);
        }

        // rotate staging buffers
        unsigned tmp = ro; ro = mo; mo = io; io = tmp;
    }
    #undef ISSUE

    // ---- denominator: quad-reduce then stash per wave ----
    #pragma unroll
    for (int nt = 0; nt < 4; ++nt) {
        lacc[nt] += __shfl_xor(lacc[nt], 16);
        lacc[nt] += __shfl_xor(lacc[nt], 32);
    }
    if (quad == 0)
        #pragma unroll
        for (int nt = 0; nt < 4; ++nt) wredl[w][nt * 16 + lq] = lacc[nt];

    // ---- cross-wave combine via LDS overlay (2 rounds) ----
    float* Ol = (float*)smem;   // [4][64 c][66] fp32 = 67584 B, overlays staging
    __syncthreads();            // all waves past vmcnt(0): staging dead; wredl visible
    if (w < 4) {
        #pragma unroll
        for (int nt = 0; nt < 4; ++nt)
            #pragma unroll
            for (int cb = 0; cb < 4; ++cb)
                #pragma unroll
                for (int r = 0; r < 4; ++r)
                    Ol[(w * 64 + 16 * cb + lq) * 66 + nt * 16 + quad * 4 + r] = o[nt][cb][r];
    }
    __syncthreads();
    if (w >= 4) {
        #pragma unroll
        for (int nt = 0; nt < 4; ++nt)
            #pragma unroll
            for (int cb = 0; cb < 4; ++cb)
                #pragma unroll
                for (int r = 0; r < 4; ++r)
                    Ol[((w - 4) * 64 + 16 * cb + lq) * 66 + nt * 16 + quad * 4 + r] += o[nt][cb][r];
    }
    __syncthreads();

    // ---- final: out[c][q0+q] = sum of 4 buffers / l_q ----
    float* og = out + (size_t)b * Cn * Pn;
    #pragma unroll
    for (int k = 0; k < 8; ++k) {
        int idx = k * 512 + t;
        int c = idx >> 6, q = idx & 63;
        float lsum = ((wredl[0][q] + wredl[1][q]) + (wredl[2][q] + wredl[3][q])) +
                     ((wredl[4][q] + wredl[5][q]) + (wredl[6][q] + wredl[7][q]));
        float v = ((Ol[c * 66 + q] + Ol[(64 + c) * 66 + q]) +
                   (Ol[(128 + c) * 66 + q] + Ol[(192 + c) * 66 + q])) / lsum;
        og[(size_t)c * Pn + q0 + q] = v;
    }
}

// ---------------------------------------------------------------------------
extern "C" void kernel_launch(void* const* d_in, const int* in_sizes, int n_in,
                              void* d_out, int out_size, void* d_ws, size_t ws_size,
                              hipStream_t stream) {
    const float* fg = (const float*)d_in[0];
    float* out = (float*)d_out;
    bfu*   Kpc  = (bfu*)d_ws;                              // 2 MB  bf16 [B][P][C]
    bfu*   Kcp2 = Kpc + (size_t)Bn * Pn * Cn;              // 2 MB  bf16 [B][P/16][C][16]
    float* S    = (float*)(Kcp2 + (size_t)Bn * Pn * Cn);   // 4 MB  fp32 [B][C][P] (pre-scaled by log2e)

    prep_kernel <<<768, 256, 0, stream>>>(fg, Kpc, Kcp2, S);
    flash_kernel<<<Bn * 64, 512, 0, stream>>>(Kpc, Kcp2, S, out);
}

// Round 5
// 94.518 us; speedup vs baseline: 1.1899x; 1.0040x over previous
//
#include <hip/hip_runtime.h>
#include <hip/hip_bf16.h>
#include <math.h>

#define Bn 4
#define Cn 64
#define Pn 4096   // 64*64
#define QT 64     // q-tile per block (256 blocks, minimal L2 traffic)
#define PBK 128   // p-block per flash iteration
#define NITER (Pn / PBK)
#define LOG2E 1.4426950408889634f

// LDS staging: 4 buffers x 32KB (A 16KB + T 16KB per 128-p tile), then Sl 8KB.
#define STG_BUF 32768
#define SL_OFF  131072         // 4*32768
#define SMEM_BYTES 139264      // SL_OFF + 8192

typedef __attribute__((ext_vector_type(8))) short short8;   // 8 bf16 (MFMA K=32 A/B frag)
typedef __attribute__((ext_vector_type(4))) short short4v;  // 4 bf16 (MFMA K=16 A/B frag)
typedef __attribute__((ext_vector_type(4))) float float4v;  // MFMA C/D frag
typedef __attribute__((ext_vector_type(2))) unsigned uint2v;
typedef unsigned short bfu;

__device__ __forceinline__ bfu f2bf(float x) {
    unsigned u = __float_as_uint(x);
    u = (u + 0x7fffu + ((u >> 16) & 1u)) >> 16;   // RNE; inputs finite
    return (bfu)u;
}

// async global->LDS, 16B per lane. LDS dest = wave-uniform base + lane*16.
__device__ __forceinline__ void gl16(const bfu* g, void* l) {
    __builtin_amdgcn_global_load_lds(
        (const __attribute__((address_space(1))) void*)g,
        (__attribute__((address_space(3))) void*)l, 16, 0, 0);
}

// ---------------------------------------------------------------------------
// Prep (unchanged): 768 blocks, 16KB LDS.
//   blocks [0,512):   knorm -> bf16 Kpc [B][P][C]  and tiled Kcp2 [B][P/16][C][16p]
//   blocks [512,768): 3x3 zero-padded box-sum * log2(e) -> S [B][C][P]
// ---------------------------------------------------------------------------
__global__ __launch_bounds__(256) void prep_kernel(const float* __restrict__ fg,
                                                   bfu* __restrict__ Kpc,
                                                   bfu* __restrict__ Kcp2,
                                                   float* __restrict__ S) {
    __shared__ float shbuf[64 * 64];
    int t = threadIdx.x;
    if (blockIdx.x < 512) {
        float* tile  = shbuf;            // [64c][32p] stride 33
        float* rnorm = shbuf + 64 * 33;
        int b  = blockIdx.x >> 7;
        int p0 = (blockIdx.x & 127) << 5;
        const float* src = fg + (size_t)b * Cn * Pn + p0;
        #pragma unroll
        for (int i = 0; i < 8; ++i) {
            int idx = i * 256 + t;
            int c = idx >> 5, p = idx & 31;
            tile[c * 33 + p] = src[(size_t)c * Pn + p];
        }
        __syncthreads();
        if (t < 32) {
            float ss = 0.f;
            #pragma unroll
            for (int c = 0; c < 64; ++c) { float v = tile[c * 33 + t]; ss += v * v; }
            rnorm[t] = 1.0f / (sqrtf(ss) + 1e-8f);
        }
        __syncthreads();
        bfu* dpc = Kpc + ((size_t)b * Pn + p0) * Cn;
        #pragma unroll
        for (int i = 0; i < 8; ++i) {
            int idx = i * 256 + t;
            int p = idx >> 6, c = idx & 63;
            dpc[(size_t)p * Cn + c] = f2bf(tile[c * 33 + p] * rnorm[p]);
        }
        // tiled transpose layout: Kcp2[b][pt][c][pl], pt = p>>4, pl = p&15
        bfu* d2 = Kcp2 + ((size_t)b * 256 + (p0 >> 4)) * 1024;
        #pragma unroll
        for (int i = 0; i < 8; ++i) {
            int idx = i * 256 + t;
            int c = idx >> 5, p = idx & 31;
            d2[(size_t)(p >> 4) * 1024 + c * 16 + (p & 15)] =
                f2bf(tile[c * 33 + p] * rnorm[p]);
        }
    } else {
        float (*pl)[64] = (float(*)[64])shbuf;
        int bc = blockIdx.x - 512;
        const float* src = fg + (size_t)bc * Pn;
        float*       dst = S  + (size_t)bc * Pn;
        #pragma unroll
        for (int i = 0; i < 16; ++i) {
            int idx = i * 256 + t;
            pl[idx >> 6][idx & 63] = src[idx];
        }
        __syncthreads();
        #pragma unroll
        for (int i = 0; i < 16; ++i) {
            int idx = i * 256 + t;
            int h = idx >> 6, w = idx & 63;
            float s = 0.f;
            #pragma unroll
            for (int dh = -1; dh <= 1; ++dh) {
                int hh = h + dh;
                if (hh < 0 || hh >= 64) continue;
                #pragma unroll
                for (int dw = -1; dw <= 1; ++dw) {
                    int ww = w + dw;
                    if (ww < 0 || ww >= 64) continue;
                    s += pl[hh][ww];
                }
            }
            dst[idx] = s * LOG2E;
        }
    }
}

// ---------------------------------------------------------------------------
// Flash (R17, resubmitted after infra failure). QT=64, 256 blocks x 512 thr.
// Wave-private async staging: 4 LDS buffers, issue tile pb+3, counted
// vmcnt(8) guarantees tile pb+1 landed; ds_read of tile pb+1's fragments
// happens during iteration pb so compute never waits on vmcnt OR lgkmcnt.
// cvt_pk_bf16_f32 pack (scalar-bound asm) halves loop VALU. setprio(1)
// around MFMA clusters (T5). No barriers inside the K-loop.
// ---------------------------------------------------------------------------
__global__ __launch_bounds__(512, 1) void flash_kernel(const bfu* __restrict__ Kpc,
                                                       const bfu* __restrict__ Kcp2,
                                                       const float* __restrict__ S,
                                                       float* __restrict__ out) {
    __shared__ __align__(16) unsigned char smem[SMEM_BYTES];
    __shared__ float wredl[8][QT];
    bfu* Sl = (bfu*)(smem + SL_OFF);       // [64q][64c] bf16, XOR-swizzled rows

    int i  = blockIdx.x;
    int b  = (i & 7) >> 1;                 // XCD-pair locality (batch per XCD pair)
    int qt = ((i >> 3) << 1) | (i & 1);    // [0,64)
    int q0 = qt * QT;
    int t  = threadIdx.x;
    int w = t >> 6, l = t & 63, lq = l & 15, quad = l >> 4;

    const float* Sg  = S    + (size_t)b * Cn * Pn;
    const bfu*   gpc = Kpc  + (size_t)b * Pn * Cn;
    const bfu*   gt  = Kcp2 + (size_t)b * 256 * 1024;   // [pt][c][pl]

    // Sl[q][c] = bf16(Sg[c][q0+q]) (S pre-scaled by log2e), XOR-swizzled rows
    {
        int c = t >> 3, qq = (t & 7) * 8;
        const float* sp = &Sg[(size_t)c * Pn + q0 + qq];
        float4 v0 = *(const float4*)sp;
        float4 v1 = *(const float4*)(sp + 4);
        float vv[8] = {v0.x, v0.y, v0.z, v0.w, v1.x, v1.y, v1.z, v1.w};
        int ch = c >> 3, cl = c & 7;
        #pragma unroll
        for (int k = 0; k < 8; ++k) {
            int row = qq + k;
            Sl[row * 64 + ((ch ^ (row & 7)) << 3) + cl] = f2bf(vv[k]);
        }
    }
    __syncthreads();   // Sl visible

    // hoist S B-frags: B[k=c][n=q], n=lq(+16nt), k=quad*8+j (+32ks)
    short8 bs[4][2];
    #pragma unroll
    for (int nt = 0; nt < 4; ++nt)
        #pragma unroll
        for (int ks = 0; ks < 2; ++ks) {
            int row = nt * 16 + lq;
            bs[nt][ks] = *(const short8*)&Sl[row * 64 + (((ks * 4 + quad) ^ (lq & 7)) << 3)];
        }

    float4v o[4][4];   // [nt][cb]: q = 16nt+4quad+r, c = 16cb+lq (wave-private p-partial)
    #pragma unroll
    for (int nt = 0; nt < 4; ++nt)
        #pragma unroll
        for (int cb = 0; cb < 4; ++cb) o[nt][cb] = (float4v){0.f, 0.f, 0.f, 0.f};
    float lacc[4] = {0.f, 0.f, 0.f, 0.f};

    // ---- per-lane staging offsets --------------------------------------
    // A-chunk [16 rows][128B]; LDS slot (row, s) holds global slot s^(row&7)
    int l8 = l >> 3, l7 = l & 7;
    int aoff = l8 * 64 + ((l7 ^ l8) << 3);       // elements; +512 per second instr
    int toff = l * 8;                            // elements; linear
    // per-lane read offsets (bytes within buffer, A at +0, T at +16KB)
    int abyte0 = lq * 128 + (((quad)     ^ (lq & 7)) << 4);
    int abyte1 = lq * 128 + (((4 + quad) ^ (lq & 7)) << 4);
    int tbyte  = 16384 + lq * 32 + quad * 8;

    unsigned wb = (unsigned)w * 2048;            // wave's sub-chunk byte base

    #define ISSUE(tile, boff)                                                      \
    {                                                                              \
        const bfu* gA = gpc + ((size_t)(tile) * PBK + (size_t)w * 16) * 64;        \
        const bfu* gT = gt + ((size_t)(tile) * 8 + w) * 1024;                      \
        gl16(gA + aoff,       smem + (boff) + wb);                                 \
        gl16(gA + 512 + aoff, smem + (boff) + wb + 1024);                          \
        gl16(gT + toff,       smem + (boff) + 16384 + wb);                         \
        gl16(gT + 512 + toff, smem + (boff) + 16384 + wb + 1024);                  \
    }

    // prologue: stage tiles 0,1,2; wait tile 0; read tile-0 fragments
    ISSUE(0, 0u);
    ISSUE(1, STG_BUF);
    ISSUE(2, 2u * STG_BUF);
    asm volatile("s_waitcnt vmcnt(8)" ::: "memory");
    short8 af0c = *(const short8*)(smem + wb + abyte0);
    short8 af1c = *(const short8*)(smem + wb + abyte1);
    short4v kbc[4];
    #pragma unroll
    for (int cb = 0; cb < 4; ++cb)
        kbc[cb] = *(const short4v*)(smem + wb + tbyte + cb * 512);

    for (int pb = 0; pb < NITER; ++pb) {
        // ---- issue tile pb+3; guarantee tile pb+1 landed ----
        if (pb + 3 < NITER) {
            ISSUE(pb + 3, (unsigned)((pb + 3) & 3) * STG_BUF);
            asm volatile("s_waitcnt vmcnt(8)" ::: "memory");
        } else if (pb == NITER - 3) {
            asm volatile("s_waitcnt vmcnt(4)" ::: "memory");
        } else if (pb == NITER - 2) {
            asm volatile("s_waitcnt vmcnt(0)" ::: "memory");
        }

        // ---- ds_read NEXT tile's fragments (latency spans this iteration) ----
        short8 af0n, af1n;
        short4v kbn[4];
        if (pb + 1 < NITER) {
            unsigned nb = (unsigned)((pb + 1) & 3) * STG_BUF;
            af0n = *(const short8*)(smem + nb + wb + abyte0);
            af1n = *(const short8*)(smem + nb + wb + abyte1);
            #pragma unroll
            for (int cb = 0; cb < 4; ++cb)
                kbn[cb] = *(const short4v*)(smem + nb + wb + tbyte + cb * 512);
        }

        // ---- score GEMM (K=32): D[m=p][n=q], 4 q-subtiles ----
        float4v sc[4];
        __builtin_amdgcn_s_setprio(1);
        #pragma unroll
        for (int nt = 0; nt < 4; ++nt) {
            float4v acc = (float4v){0.f, 0.f, 0.f, 0.f};
            acc = __builtin_amdgcn_mfma_f32_16x16x32_bf16(af0c, bs[nt][0], acc, 0, 0, 0);
            acc = __builtin_amdgcn_mfma_f32_16x16x32_bf16(af1c, bs[nt][1], acc, 0, 0, 0);
            sc[nt] = acc;
        }
        __builtin_amdgcn_s_setprio(0);

        // ---- exp2 + denominator; cvt_pk packs E as K=16 A-frags ----
        short4v epk[4];
        #pragma unroll
        for (int nt = 0; nt < 4; ++nt) {
            float e0 = __builtin_amdgcn_exp2f(sc[nt][0]);
            float e1 = __builtin_amdgcn_exp2f(sc[nt][1]);
            float e2 = __builtin_amdgcn_exp2f(sc[nt][2]);
            float e3 = __builtin_amdgcn_exp2f(sc[nt][3]);
            lacc[nt] += (e0 + e1) + (e2 + e3);
            unsigned plo, phi;
            asm("v_cvt_pk_bf16_f32 %0, %1, %2" : "=v"(plo) : "v"(e0), "v"(e1));
            asm("v_cvt_pk_bf16_f32 %0, %1, %2" : "=v"(phi) : "v"(e2), "v"(e3));
            uint2v pk2 = {plo, phi};
            epk[nt] = __builtin_bit_cast(short4v, pk2);
        }

        // ---- accum GEMM (K=16): o'[q][c] += E · Kcp2 frags ----
        __builtin_amdgcn_s_setprio(1);
        #pragma unroll
        for (int cb = 0; cb < 4; ++cb) {
            #pragma unroll
            for (int nt = 0; nt < 4; ++nt)
                o[nt][cb] = __builtin_amdgcn_mfma_f32_16x16x16bf16_1k(epk[nt], kbc[cb], o[nt][cb], 0, 0, 0);
        }
        __builtin_amdgcn_s_setprio(0);

        // rotate fragments
        if (pb + 1 < NITER) {
            af0c = af0n; af1c = af1n;
            #pragma unroll
            for (int cb = 0; cb < 4; ++cb) kbc[cb] = kbn[cb];
        }
    }
    #undef ISSUE

    // ---- denominator: quad-reduce then stash per wave ----
    #pragma unroll
    for (int nt = 0; nt < 4; ++nt) {
        lacc[nt] += __shfl_xor(lacc[nt], 16);
        lacc[nt] += __shfl_xor(lacc[nt], 32);
    }
    if (quad == 0)
        #pragma unroll
        for (int nt = 0; nt < 4; ++nt) wredl[w][nt * 16 + lq] = lacc[nt];

    // ---- cross-wave combine via LDS overlay (2 rounds) ----
    float* Ol = (float*)smem;   // [4][64 c][66] fp32 = 67584 B, overlays staging
    __syncthreads();            // staging dead; wredl visible
    if (w < 4) {
        #pragma unroll
        for (int nt = 0; nt < 4; ++nt)
            #pragma unroll
            for (int cb = 0; cb < 4; ++cb)
                #pragma unroll
                for (int r = 0; r < 4; ++r)
                    Ol[(w * 64 + 16 * cb + lq) * 66 + nt * 16 + quad * 4 + r] = o[nt][cb][r];
    }
    __syncthreads();
    if (w >= 4) {
        #pragma unroll
        for (int nt = 0; nt < 4; ++nt)
            #pragma unroll
            for (int cb = 0; cb < 4; ++cb)
                #pragma unroll
                for (int r = 0; r < 4; ++r)
                    Ol[((w - 4) * 64 + 16 * cb + lq) * 66 + nt * 16 + quad * 4 + r] += o[nt][cb][r];
    }
    __syncthreads();

    // ---- final: out[c][q0+q] = sum of 4 buffers / l_q ----
    float* og = out + (size_t)b * Cn * Pn;
    #pragma unroll
    for (int k = 0; k < 8; ++k) {
        int idx = k * 512 + t;
        int c = idx >> 6, q = idx & 63;
        float lsum = ((wredl[0][q] + wredl[1][q]) + (wredl[2][q] + wredl[3][q])) +
                     ((wredl[4][q] + wredl[5][q]) + (wredl[6][q] + wredl[7][q]));
        float v = ((Ol[c * 66 + q] + Ol[(64 + c) * 66 + q]) +
                   (Ol[(128 + c) * 66 + q] + Ol[(192 + c) * 66 + q])) / lsum;
        og[(size_t)c * Pn + q0 + q] = v;
    }
}

// ---------------------------------------------------------------------------
extern "C" void kernel_launch(void* const* d_in, const int* in_sizes, int n_in,
                              void* d_out, int out_size, void* d_ws, size_t ws_size,
                              hipStream_t stream) {
    const float* fg = (const float*)d_in[0];
    float* out = (float*)d_out;
    bfu*   Kpc  = (bfu*)d_ws;                              // 2 MB  bf16 [B][P][C]
    bfu*   Kcp2 = Kpc + (size_t)Bn * Pn * Cn;              // 2 MB  bf16 [B][P/16][C][16]
    float* S    = (float*)(Kcp2 + (size_t)Bn * Pn * Cn);   // 4 MB  fp32 [B][C][P] (pre-scaled by log2e)

    prep_kernel <<<768, 256, 0, stream>>>(fg, Kpc, Kcp2, S);
    flash_kernel<<<Bn * 64, 512, 0, stream>>>(Kpc, Kcp2, S, out);
}

// Round 6
// 94.021 us; speedup vs baseline: 1.1962x; 1.0053x over previous
//
#include <hip/hip_runtime.h>
#include <hip/hip_bf16.h>
#include <math.h>

#define Bn 4
#define Cn 64
#define Pn 4096   // 64*64
#define QT 64     // q-tile per block
#define PBK 128   // p-block per flash iteration
#define NITER (Pn / PBK)
#define LOG2E 1.4426950408889634f

typedef __attribute__((ext_vector_type(8))) short short8;   // 8 bf16 (MFMA K=32 A/B frag)
typedef __attribute__((ext_vector_type(4))) short short4v;  // 4 bf16 (MFMA K=16 A/B frag)
typedef __attribute__((ext_vector_type(4))) float float4v;  // MFMA C/D frag
typedef unsigned short bfu;

__device__ __forceinline__ bfu f2bf(float x) {
    unsigned u = __float_as_uint(x);
    u = (u + 0x7fffu + ((u >> 16) & 1u)) >> 16;   // RNE; inputs finite
    return (bfu)u;
}

// ---------------------------------------------------------------------------
// Prep (unchanged): 768 blocks, 16KB LDS.
//   blocks [0,512):   knorm -> bf16 Kpc [B][P][C]  and tiled Kcp2 [B][P/16][C][16p]
//   blocks [512,768): 3x3 zero-padded box-sum * log2(e) -> S [B][C][P]
// ---------------------------------------------------------------------------
__global__ __launch_bounds__(256) void prep_kernel(const float* __restrict__ fg,
                                                   bfu* __restrict__ Kpc,
                                                   bfu* __restrict__ Kcp2,
                                                   float* __restrict__ S) {
    __shared__ float shbuf[64 * 64];
    int t = threadIdx.x;
    if (blockIdx.x < 512) {
        float* tile  = shbuf;            // [64c][32p] stride 33
        float* rnorm = shbuf + 64 * 33;
        int b  = blockIdx.x >> 7;
        int p0 = (blockIdx.x & 127) << 5;
        const float* src = fg + (size_t)b * Cn * Pn + p0;
        #pragma unroll
        for (int i = 0; i < 8; ++i) {
            int idx = i * 256 + t;
            int c = idx >> 5, p = idx & 31;
            tile[c * 33 + p] = src[(size_t)c * Pn + p];
        }
        __syncthreads();
        if (t < 32) {
            float ss = 0.f;
            #pragma unroll
            for (int c = 0; c < 64; ++c) { float v = tile[c * 33 + t]; ss += v * v; }
            rnorm[t] = 1.0f / (sqrtf(ss) + 1e-8f);
        }
        __syncthreads();
        bfu* dpc = Kpc + ((size_t)b * Pn + p0) * Cn;
        #pragma unroll
        for (int i = 0; i < 8; ++i) {
            int idx = i * 256 + t;
            int p = idx >> 6, c = idx & 63;
            dpc[(size_t)p * Cn + c] = f2bf(tile[c * 33 + p] * rnorm[p]);
        }
        // tiled transpose layout: Kcp2[b][pt][c][pl], pt = p>>4, pl = p&15
        bfu* d2 = Kcp2 + ((size_t)b * 256 + (p0 >> 4)) * 1024;
        #pragma unroll
        for (int i = 0; i < 8; ++i) {
            int idx = i * 256 + t;
            int c = idx >> 5, p = idx & 31;
            d2[(size_t)(p >> 4) * 1024 + c * 16 + (p & 15)] =
                f2bf(tile[c * 33 + p] * rnorm[p]);
        }
    } else {
        float (*pl)[64] = (float(*)[64])shbuf;
        int bc = blockIdx.x - 512;
        const float* src = fg + (size_t)bc * Pn;
        float*       dst = S  + (size_t)bc * Pn;
        #pragma unroll
        for (int i = 0; i < 16; ++i) {
            int idx = i * 256 + t;
            pl[idx >> 6][idx & 63] = src[idx];
        }
        __syncthreads();
        #pragma unroll
        for (int i = 0; i < 16; ++i) {
            int idx = i * 256 + t;
            int h = idx >> 6, w = idx & 63;
            float s = 0.f;
            #pragma unroll
            for (int dh = -1; dh <= 1; ++dh) {
                int hh = h + dh;
                if (hh < 0 || hh >= 64) continue;
                #pragma unroll
                for (int dw = -1; dw <= 1; ++dw) {
                    int ww = w + dw;
                    if (ww < 0 || ww >= 64) continue;
                    s += pl[hh][ww];
                }
            }
            dst[idx] = s * LOG2E;
        }
    }
}

// ---------------------------------------------------------------------------
// Flash (R18) = R0 champion structure (zero-LDS K-loop, register prefetch)
// + two deltas:
//  (1) staggered wave start (~128*w cyc, s_sleep once before the loop; no
//      in-loop barrier ever re-syncs) so the 8 waves sit at spread code
//      phases: exp2/trans, MFMA and VMEM use interleave across waves
//      instead of colliding in lockstep.
//  (2) #pragma unroll 2 on the K-loop: prefetch rotate becomes register
//      renaming (removes ~24 dword copies/iter).
// Wave w owns p-rows [16w,16w+16) of each 128-p block end-to-end:
//   score: A = global Kpc rows (dwordx4), B = hoisted S frags (K=32 MFMA x8)
//   exp'd scores -> register K=16 A-frags (C-layout == A-layout)
//   accum: B = global Kcp2 frags (dwordx2), K=16 MFMA x16; loads prefetched
//   one iteration ahead. No LDS, no barriers inside the loop.
// ---------------------------------------------------------------------------
__global__ __launch_bounds__(512, 1) void flash_kernel(const bfu* __restrict__ Kpc,
                                                       const bfu* __restrict__ Kcp2,
                                                       const float* __restrict__ S,
                                                       float* __restrict__ out) {
    // Sl lives in [0,8192) bfu; epilogue Ol fp32 [4][64][66] overlays all 67.5 KB
    __shared__ __align__(16) bfu smem[33792];
    __shared__ float wredl[8][QT];
    bfu* Sl = smem;

    int i  = blockIdx.x;
    int b  = (i & 7) >> 1;                       // XCD-pair locality
    int qt = ((i >> 3) << 1) | (i & 1);
    int q0 = qt * QT;
    int t  = threadIdx.x;
    int w = t >> 6, l = t & 63, lq = l & 15, quad = l >> 4;

    const float* Sg  = S    + (size_t)b * Cn * Pn;
    const bfu*   gpc = Kpc  + (size_t)b * Pn * Cn;
    const bfu*   gt  = Kcp2 + (size_t)b * 256 * 1024;   // [pt][c][pl]

    // Sl[q][c] = bf16(Sg[c][q0+q]) (S pre-scaled by log2e), XOR-swizzled rows
    {
        int c = t >> 3, qq = (t & 7) * 8;
        const float* sp = &Sg[(size_t)c * Pn + q0 + qq];
        float4 v0 = *(const float4*)sp;
        float4 v1 = *(const float4*)(sp + 4);
        float vv[8] = {v0.x, v0.y, v0.z, v0.w, v1.x, v1.y, v1.z, v1.w};
        int ch = c >> 3, cl = c & 7;
        #pragma unroll
        for (int k = 0; k < 8; ++k) {
            int row = qq + k;
            Sl[row * 64 + ((ch ^ (row & 7)) << 3) + cl] = f2bf(vv[k]);
        }
    }
    __syncthreads();   // Sl visible

    // hoist S B-frags: B[k=c][n=q], n=lq(+16nt), k=quad*8+j (+32ks)
    short8 bs[4][2];
    #pragma unroll
    for (int nt = 0; nt < 4; ++nt)
        #pragma unroll
        for (int ks = 0; ks < 2; ++ks) {
            int row = nt * 16 + lq;
            bs[nt][ks] = *(const short8*)&Sl[row * 64 + (((ks * 4 + quad) ^ (lq & 7)) << 3)];
        }

    // R18: stagger wave start ~128*w cycles to desynchronize code phases
    // (exp2/trans vs MFMA vs VMEM) across the 8 waves. No in-loop barrier
    // re-syncs, so offsets persist through the K-loop.
    switch (w) {
        case 1: __builtin_amdgcn_s_sleep(2);  break;
        case 2: __builtin_amdgcn_s_sleep(4);  break;
        case 3: __builtin_amdgcn_s_sleep(6);  break;
        case 4: __builtin_amdgcn_s_sleep(8);  break;
        case 5: __builtin_amdgcn_s_sleep(10); break;
        case 6: __builtin_amdgcn_s_sleep(12); break;
        case 7: __builtin_amdgcn_s_sleep(14); break;
        default: break;
    }

    float4v o[4][4];   // [nt][cb]: q = 16nt+4quad+r, c = 16cb+lq (wave-private p-partial)
    #pragma unroll
    for (int nt = 0; nt < 4; ++nt)
        #pragma unroll
        for (int cb = 0; cb < 4; ++cb) o[nt][cb] = (float4v){0.f, 0.f, 0.f, 0.f};
    float lacc[4] = {0.f, 0.f, 0.f, 0.f};

    // per-wave global addresses (advance by constants each iteration)
    const bfu* ap = gpc + ((size_t)16 * w + lq) * Cn + quad * 8;           // score A rows
    const bfu* tp = gt + (size_t)w * 1024 + lq * 16 + quad * 4;            // accum B frags

    // prologue: load pb=0 operands
    float4 a0 = *(const float4*)ap;
    float4 a1 = *(const float4*)(ap + 32);
    short4v kb[4];
    #pragma unroll
    for (int cb = 0; cb < 4; ++cb) kb[cb] = *(const short4v*)(tp + cb * 256);

    #pragma unroll 2
    for (int pb = 0; pb < NITER; ++pb) {
        // ---- prefetch pb+1 operands (independent; compiler issues early) ----
        float4 na0, na1;
        short4v nkb[4];
        if (pb + 1 < NITER) {
            const bfu* apn = ap + (size_t)(pb + 1) * PBK * Cn;
            na0 = *(const float4*)apn;
            na1 = *(const float4*)(apn + 32);
            const bfu* tpn = tp + (size_t)(pb + 1) * 8 * 1024;
            #pragma unroll
            for (int cb = 0; cb < 4; ++cb) nkb[cb] = *(const short4v*)(tpn + cb * 256);
        }

        // ---- score GEMM (K=32): D[m=p][n=q], 4 q-subtiles ----
        short8 af0 = *(short8*)&a0, af1 = *(short8*)&a1;
        float4v sc[4];
        #pragma unroll
        for (int nt = 0; nt < 4; ++nt) {
            float4v acc = (float4v){0.f, 0.f, 0.f, 0.f};
            acc = __builtin_amdgcn_mfma_f32_16x16x32_bf16(af0, bs[nt][0], acc, 0, 0, 0);
            acc = __builtin_amdgcn_mfma_f32_16x16x32_bf16(af1, bs[nt][1], acc, 0, 0, 0);
            sc[nt] = acc;
        }

        // ---- exp2 + denominator; pack E directly as K=16 A-frags ----
        short4v epk[4];
        #pragma unroll
        for (int nt = 0; nt < 4; ++nt) {
            float e0 = __builtin_amdgcn_exp2f(sc[nt][0]);
            float e1 = __builtin_amdgcn_exp2f(sc[nt][1]);
            float e2 = __builtin_amdgcn_exp2f(sc[nt][2]);
            float e3 = __builtin_amdgcn_exp2f(sc[nt][3]);
            lacc[nt] += (e0 + e1) + (e2 + e3);
            short4v ep = {(short)f2bf(e0), (short)f2bf(e1), (short)f2bf(e2), (short)f2bf(e3)};
            epk[nt] = ep;
        }

        // ---- accum GEMM (K=16): o'[q][c] += E · Kcp2 frags ----
        #pragma unroll
        for (int cb = 0; cb < 4; ++cb) {
            #pragma unroll
            for (int nt = 0; nt < 4; ++nt)
                o[nt][cb] = __builtin_amdgcn_mfma_f32_16x16x16bf16_1k(epk[nt], kb[cb], o[nt][cb], 0, 0, 0);
        }

        // rotate prefetched operands (renamed away by unroll 2)
        a0 = na0; a1 = na1;
        #pragma unroll
        for (int cb = 0; cb < 4; ++cb) kb[cb] = nkb[cb];
    }

    // ---- denominator: quad-reduce then stash per wave ----
    #pragma unroll
    for (int nt = 0; nt < 4; ++nt) {
        lacc[nt] += __shfl_xor(lacc[nt], 16);
        lacc[nt] += __shfl_xor(lacc[nt], 32);
    }
    if (quad == 0)
        #pragma unroll
        for (int nt = 0; nt < 4; ++nt) wredl[w][nt * 16 + lq] = lacc[nt];

    // ---- cross-wave combine via LDS overlay (2 rounds) ----
    float* Ol = (float*)smem;   // [4][64 c][66] fp32 = 67584 B
    __syncthreads();            // Sl reads done; wredl visible
    if (w < 4) {
        #pragma unroll
        for (int nt = 0; nt < 4; ++nt)
            #pragma unroll
            for (int cb = 0; cb < 4; ++cb)
                #pragma unroll
                for (int r = 0; r < 4; ++r)
                    Ol[(w * 64 + 16 * cb + lq) * 66 + nt * 16 + quad * 4 + r] = o[nt][cb][r];
    }
    __syncthreads();
    if (w >= 4) {
        #pragma unroll
        for (int nt = 0; nt < 4; ++nt)
            #pragma unroll
            for (int cb = 0; cb < 4; ++cb)
                #pragma unroll
                for (int r = 0; r < 4; ++r)
                    Ol[((w - 4) * 64 + 16 * cb + lq) * 66 + nt * 16 + quad * 4 + r] += o[nt][cb][r];
    }
    __syncthreads();

    // ---- final: out[c][q0+q] = sum of 4 buffers / l_q ----
    float* og = out + (size_t)b * Cn * Pn;
    #pragma unroll
    for (int k = 0; k < 8; ++k) {
        int idx = k * 512 + t;
        int c = idx >> 6, q = idx & 63;
        float lsum = ((wredl[0][q] + wredl[1][q]) + (wredl[2][q] + wredl[3][q])) +
                     ((wredl[4][q] + wredl[5][q]) + (wredl[6][q] + wredl[7][q]));
        float v = ((Ol[c * 66 + q] + Ol[(64 + c) * 66 + q]) +
                   (Ol[(128 + c) * 66 + q] + Ol[(192 + c) * 66 + q])) / lsum;
        og[(size_t)c * Pn + q0 + q] = v;
    }
}

// ---------------------------------------------------------------------------
extern "C" void kernel_launch(void* const* d_in, const int* in_sizes, int n_in,
                              void* d_out, int out_size, void* d_ws, size_t ws_size,
                              hipStream_t stream) {
    const float* fg = (const float*)d_in[0];
    float* out = (float*)d_out;
    bfu*   Kpc  = (bfu*)d_ws;                              // 2 MB  bf16 [B][P][C]
    bfu*   Kcp2 = Kpc + (size_t)Bn * Pn * Cn;              // 2 MB  bf16 [B][P/16][C][16]
    float* S    = (float*)(Kcp2 + (size_t)Bn * Pn * Cn);   // 4 MB  fp32 [B][C][P] (pre-scaled by log2e)

    prep_kernel <<<768, 256, 0, stream>>>(fg, Kpc, Kcp2, S);
    flash_kernel<<<Bn * 64, 512, 0, stream>>>(Kpc, Kcp2, S, out);
}